// Round 1
// baseline (1141.851 us; speedup 1.0000x reference)
//
#include <hip/hip_runtime.h>

#define PH 7
#define PW 7
#define SR 2
#define SY (PH * SR)   // 14
#define SX (PW * SR)   // 14
#define CH 256
#define FH 200
#define FW 272
#define BINS (PH * PW) // 49

__global__ __launch_bounds__(256) void roialign_kernel(
    const float* __restrict__ feat,
    const float* __restrict__ rois,
    float* __restrict__ out,
    int N) {
    // Per-ROI separable sample descriptors (shared across all channels)
    __shared__ int   s_yl[SY], s_yh[SY];
    __shared__ float s_ly[SY], s_hy[SY];   // y-weights, valid_y folded in
    __shared__ int   s_xl[SX], s_xh[SX];
    __shared__ float s_lx[SX], s_hx[SX];   // x-weights, valid_x folded in
    __shared__ float s_out[CH * BINS];     // 50176 B staging for coalesced write

    const int n   = blockIdx.x;
    const int tid = threadIdx.x;
    const float* __restrict__ roi = rois + (size_t)n * 5;

    if (tid < SY + SX) {
        const bool isy = (tid < SY);
        const int  idx = isy ? tid : tid - SY;
        const int  lim = isy ? FH : FW;
        const float start = (isy ? roi[2] : roi[1]) * 0.25f;
        const float end_  = (isy ? roi[4] : roi[3]) * 0.25f;
        const float len   = fmaxf(end_ - start, 1.0f);
        const float binsz = len * (isy ? (1.0f / PH) : (1.0f / PW));
        // sample coord = start + ((idx + 0.5)/SR) * binsz
        const float s = start + ((float)idx + 0.5f) * (1.0f / SR) * binsz;
        const float valid = (s > -1.0f && s < (float)lim) ? 1.0f : 0.0f;
        const float c  = fminf(fmaxf(s, 0.0f), (float)(lim - 1));
        const int   lo = (int)floorf(c);
        const int   hi = min(lo + 1, lim - 1);
        const float l  = (c - (float)lo) * valid;
        const float h  = (1.0f - (c - (float)lo)) * valid;
        if (isy) { s_yl[idx] = lo; s_yh[idx] = hi; s_ly[idx] = l; s_hy[idx] = h; }
        else     { s_xl[idx] = lo; s_xh[idx] = hi; s_lx[idx] = l; s_hx[idx] = h; }
    }
    __syncthreads();

    // batch index: wave-uniform scalar load
    const int b = (int)roi[0];
    const int c = tid; // one thread per channel (CH == blockDim.x == 256)
    const float* __restrict__ fp = feat + ((size_t)b * CH + c) * (size_t)(FH * FW);

    #pragma unroll 1
    for (int ph = 0; ph < PH; ++ph) {
        const int sy0 = ph * SR;
        const int yl0 = s_yl[sy0],     yh0 = s_yh[sy0];
        const int yl1 = s_yl[sy0 + 1], yh1 = s_yh[sy0 + 1];
        const float ly0 = s_ly[sy0],     hy0 = s_hy[sy0];
        const float ly1 = s_ly[sy0 + 1], hy1 = s_hy[sy0 + 1];
        const float* r00 = fp + yl0 * FW;
        const float* r01 = fp + yh0 * FW;
        const float* r10 = fp + yl1 * FW;
        const float* r11 = fp + yh1 * FW;
        for (int pw = 0; pw < PW; ++pw) {
            const int sx0 = pw * SR;
            float acc = 0.0f;
            #pragma unroll
            for (int j = 0; j < SR; ++j) {
                const int   xl = s_xl[sx0 + j], xh = s_xh[sx0 + j];
                const float lx = s_lx[sx0 + j], hx = s_hx[sx0 + j];
                // sample row i=0
                acc += hy0 * (hx * r00[xl] + lx * r00[xh])
                     + ly0 * (hx * r01[xl] + lx * r01[xh]);
                // sample row i=1
                acc += hy1 * (hx * r10[xl] + lx * r10[xh])
                     + ly1 * (hx * r11[xl] + lx * r11[xh]);
            }
            s_out[c * BINS + ph * PW + pw] = acc * 0.25f;
        }
    }
    __syncthreads();

    // Coalesced flush of this ROI's [C, 7, 7] tile
    float* __restrict__ outn = out + (size_t)n * (CH * BINS);
    #pragma unroll
    for (int k = 0; k < BINS; ++k) {
        const int idx = k * 256 + tid;
        outn[idx] = s_out[idx];
    }
}

extern "C" void kernel_launch(void* const* d_in, const int* in_sizes, int n_in,
                              void* d_out, int out_size, void* d_ws, size_t ws_size,
                              hipStream_t stream) {
    const float* feat = (const float*)d_in[0];
    const float* rois = (const float*)d_in[1];
    float* out = (float*)d_out;
    const int N = in_sizes[1] / 5;
    roialign_kernel<<<N, 256, 0, stream>>>(feat, rois, out, N);
}

// Round 2
// 336.574 us; speedup vs baseline: 3.3926x; 3.3926x over previous
//
#include <hip/hip_runtime.h>

#define PH 7
#define PW 7
#define SR 2
#define SY (PH * SR)   // 14
#define SX (PW * SR)   // 14
#define CH 256
#define FH 200
#define FW 272
#define BINS (PH * PW) // 49
#define NPIX (FH * FW) // 54400

// ---------- Pass 1: transpose feat [B,C,H,W] -> featT [B,H,W,C] ----------
__global__ __launch_bounds__(256) void transpose_kernel(
    const float* __restrict__ feat, float* __restrict__ featT) {
    __shared__ float tile[64][65];
    const int w0 = blockIdx.x * 64;
    const int c0 = blockIdx.y * 64;
    const int bh = blockIdx.z;           // b*FH + h
    const int tx = threadIdx.x;          // 0..63
    const int ty = threadIdx.y;          // 0..3
    const int b  = bh / FH;
    const int h  = bh % FH;
    const float* __restrict__ src = feat + (size_t)b * CH * NPIX + (size_t)h * FW;
    if (w0 + tx < FW) {
        #pragma unroll
        for (int k = 0; k < 16; ++k) {
            const int c = c0 + ty + 4 * k;
            tile[ty + 4 * k][tx] = src[(size_t)c * NPIX + w0 + tx];  // coalesced in w
        }
    }
    __syncthreads();
    float* __restrict__ dst = featT + (size_t)bh * FW * CH;
    #pragma unroll
    for (int k = 0; k < 16; ++k) {
        const int w = w0 + ty + 4 * k;
        if (w < FW) dst[(size_t)w * CH + c0 + tx] = tile[tx][ty + 4 * k]; // coalesced in c
    }
}

// ---------- Pass 2: ROIAlign on channels-last featT ----------
__global__ __launch_bounds__(256) void roialign_cl_kernel(
    const float* __restrict__ featT,
    const float* __restrict__ rois,
    float* __restrict__ out, int N) {
    // Separable sample descriptors; x/y indices pre-scaled to element offsets
    __shared__ int   s_yl[SY], s_yh[SY];   // row offset = y * FW * CH
    __shared__ float s_ly[SY], s_hy[SY];
    __shared__ int   s_xl[SX], s_xh[SX];   // col offset = x * CH
    __shared__ float s_lx[SX], s_hx[SX];

    const int n   = blockIdx.x;
    const int tid = threadIdx.x;
    const float* __restrict__ roi = rois + (size_t)n * 5;

    if (tid < SY + SX) {
        const bool isy = (tid < SY);
        const int  idx = isy ? tid : tid - SY;
        const int  lim = isy ? FH : FW;
        const float start = (isy ? roi[2] : roi[1]) * 0.25f;
        const float end_  = (isy ? roi[4] : roi[3]) * 0.25f;
        const float len   = fmaxf(end_ - start, 1.0f);
        const float binsz = len * (isy ? (1.0f / PH) : (1.0f / PW));
        const float s = start + ((float)idx + 0.5f) * (1.0f / SR) * binsz;
        const float valid = (s > -1.0f && s < (float)lim) ? 1.0f : 0.0f;
        const float cc = fminf(fmaxf(s, 0.0f), (float)(lim - 1));
        const int   lo = (int)floorf(cc);
        const int   hi = min(lo + 1, lim - 1);
        const float l  = (cc - (float)lo) * valid;
        const float hw = (1.0f - (cc - (float)lo)) * valid;
        if (isy) { s_yl[idx] = lo * (FW * CH); s_yh[idx] = hi * (FW * CH);
                   s_ly[idx] = l; s_hy[idx] = hw; }
        else     { s_xl[idx] = lo * CH;        s_xh[idx] = hi * CH;
                   s_lx[idx] = l; s_hx[idx] = hw; }
    }
    __syncthreads();

    const int b = (int)roi[0];
    const int c = tid;   // one thread per channel; lanes read consecutive floats
    const float* __restrict__ fb = featT + (size_t)b * (FH * FW * CH) + c;
    float* __restrict__ outp = out + (size_t)n * (CH * BINS) + (size_t)c * BINS;

    #pragma unroll 1
    for (int ph = 0; ph < PH; ++ph) {
        const int sy0 = ph * SR;
        const float* r00 = fb + s_yl[sy0];
        const float* r01 = fb + s_yh[sy0];
        const float* r10 = fb + s_yl[sy0 + 1];
        const float* r11 = fb + s_yh[sy0 + 1];
        const float ly0 = s_ly[sy0],     hy0 = s_hy[sy0];
        const float ly1 = s_ly[sy0 + 1], hy1 = s_hy[sy0 + 1];
        for (int pw = 0; pw < PW; ++pw) {
            const int sx0 = pw * SR;
            float acc = 0.0f;
            #pragma unroll
            for (int j = 0; j < SR; ++j) {
                const int   xl = s_xl[sx0 + j], xh = s_xh[sx0 + j];
                const float lx = s_lx[sx0 + j], hx = s_hx[sx0 + j];
                acc += hy0 * (hx * r00[xl] + lx * r00[xh])
                     + ly0 * (hx * r01[xl] + lx * r01[xh]);
                acc += hy1 * (hx * r10[xl] + lx * r10[xh])
                     + ly1 * (hx * r11[xl] + lx * r11[xh]);
            }
            outp[ph * PW + pw] = acc * 0.25f;
        }
    }
}

// ---------- Fallback (R0 kernel) if workspace is too small ----------
__global__ __launch_bounds__(256) void roialign_kernel(
    const float* __restrict__ feat,
    const float* __restrict__ rois,
    float* __restrict__ out, int N) {
    __shared__ int   s_yl[SY], s_yh[SY];
    __shared__ float s_ly[SY], s_hy[SY];
    __shared__ int   s_xl[SX], s_xh[SX];
    __shared__ float s_lx[SX], s_hx[SX];
    __shared__ float s_out[CH * BINS];

    const int n   = blockIdx.x;
    const int tid = threadIdx.x;
    const float* __restrict__ roi = rois + (size_t)n * 5;

    if (tid < SY + SX) {
        const bool isy = (tid < SY);
        const int  idx = isy ? tid : tid - SY;
        const int  lim = isy ? FH : FW;
        const float start = (isy ? roi[2] : roi[1]) * 0.25f;
        const float end_  = (isy ? roi[4] : roi[3]) * 0.25f;
        const float len   = fmaxf(end_ - start, 1.0f);
        const float binsz = len * (isy ? (1.0f / PH) : (1.0f / PW));
        const float s = start + ((float)idx + 0.5f) * (1.0f / SR) * binsz;
        const float valid = (s > -1.0f && s < (float)lim) ? 1.0f : 0.0f;
        const float cc = fminf(fmaxf(s, 0.0f), (float)(lim - 1));
        const int   lo = (int)floorf(cc);
        const int   hi = min(lo + 1, lim - 1);
        const float l  = (cc - (float)lo) * valid;
        const float hw = (1.0f - (cc - (float)lo)) * valid;
        if (isy) { s_yl[idx] = lo; s_yh[idx] = hi; s_ly[idx] = l; s_hy[idx] = hw; }
        else     { s_xl[idx] = lo; s_xh[idx] = hi; s_lx[idx] = l; s_hx[idx] = hw; }
    }
    __syncthreads();

    const int b = (int)roi[0];
    const int c = tid;
    const float* __restrict__ fp = feat + ((size_t)b * CH + c) * (size_t)NPIX;

    #pragma unroll 1
    for (int ph = 0; ph < PH; ++ph) {
        const int sy0 = ph * SR;
        const float* r00 = fp + s_yl[sy0] * FW;
        const float* r01 = fp + s_yh[sy0] * FW;
        const float* r10 = fp + s_yl[sy0 + 1] * FW;
        const float* r11 = fp + s_yh[sy0 + 1] * FW;
        const float ly0 = s_ly[sy0],     hy0 = s_hy[sy0];
        const float ly1 = s_ly[sy0 + 1], hy1 = s_hy[sy0 + 1];
        for (int pw = 0; pw < PW; ++pw) {
            const int sx0 = pw * SR;
            float acc = 0.0f;
            #pragma unroll
            for (int j = 0; j < SR; ++j) {
                const int   xl = s_xl[sx0 + j], xh = s_xh[sx0 + j];
                const float lx = s_lx[sx0 + j], hx = s_hx[sx0 + j];
                acc += hy0 * (hx * r00[xl] + lx * r00[xh])
                     + ly0 * (hx * r01[xl] + lx * r01[xh]);
                acc += hy1 * (hx * r10[xl] + lx * r10[xh])
                     + ly1 * (hx * r11[xl] + lx * r11[xh]);
            }
            s_out[c * BINS + ph * PW + pw] = acc * 0.25f;
        }
    }
    __syncthreads();

    float* __restrict__ outn = out + (size_t)n * (CH * BINS);
    #pragma unroll
    for (int k = 0; k < BINS; ++k) {
        const int idx = k * 256 + tid;
        outn[idx] = s_out[idx];
    }
}

extern "C" void kernel_launch(void* const* d_in, const int* in_sizes, int n_in,
                              void* d_out, int out_size, void* d_ws, size_t ws_size,
                              hipStream_t stream) {
    const float* feat = (const float*)d_in[0];
    const float* rois = (const float*)d_in[1];
    float* out = (float*)d_out;
    const int N = in_sizes[1] / 5;
    const int B = in_sizes[0] / (CH * NPIX);
    const size_t need = (size_t)B * CH * NPIX * sizeof(float);

    if (ws_size >= need) {
        float* featT = (float*)d_ws;
        dim3 tgrid((FW + 63) / 64, CH / 64, B * FH);
        transpose_kernel<<<tgrid, dim3(64, 4), 0, stream>>>(feat, featT);
        roialign_cl_kernel<<<N, 256, 0, stream>>>(featT, rois, out, N);
    } else {
        roialign_kernel<<<N, 256, 0, stream>>>(feat, rois, out, N);
    }
}

// Round 3
// 229.394 us; speedup vs baseline: 4.9777x; 1.4672x over previous
//
#include <hip/hip_runtime.h>

#define PH 7
#define PW 7
#define SR 2
#define SY (PH * SR)   // 14
#define SX (PW * SR)   // 14
#define CH 256
#define FH 200
#define FW 272
#define BINS (PH * PW) // 49
#define NPIX (FH * FW) // 54400

__device__ __forceinline__ unsigned short f2bf(float f) {
    unsigned x = __float_as_uint(f);
    return (unsigned short)((x + 0x7fffu + ((x >> 16) & 1u)) >> 16);
}
__device__ __forceinline__ float bflo(unsigned u) { return __uint_as_float(u << 16); }
__device__ __forceinline__ float bfhi(unsigned u) { return __uint_as_float(u & 0xffff0000u); }

// ---------- Pass 1: feat [B,C,H,W] fp32 -> featT [B,H,W,C] bf16 ----------
__global__ __launch_bounds__(256) void transpose_kernel(
    const float* __restrict__ feat, unsigned short* __restrict__ featT) {
    __shared__ float tile[64][65];            // [w_local][c_local]
    const int t  = threadIdx.x;
    const int w0 = blockIdx.x * 64;
    const int c0 = blockIdx.y * 64;
    const int bh = blockIdx.z;                // b*FH + h
    const int b  = bh / FH;
    const int h  = bh % FH;

    // Load: float4 along w (coalesced 1 KB/wave)
    const int wq = t & 15;                    // w quad index
    const int cl = t >> 4;                    // 0..15
    if (w0 + wq * 4 < FW) {
        const size_t base = (size_t)b * CH * NPIX + (size_t)h * FW + w0 + wq * 4;
        #pragma unroll
        for (int k = 0; k < 4; ++k) {
            const int c = cl + 16 * k;
            const float4 v = *(const float4*)(feat + base + (size_t)(c0 + c) * NPIX);
            tile[wq * 4 + 0][c] = v.x;
            tile[wq * 4 + 1][c] = v.y;
            tile[wq * 4 + 2][c] = v.z;
            tile[wq * 4 + 3][c] = v.w;
        }
    }
    __syncthreads();

    // Store: bf16 pairs along c (coalesced)
    const int cd = t & 31;                    // c pair index
    const int wl = t >> 5;                    // 0..7
    unsigned* __restrict__ dstu = (unsigned*)featT;
    #pragma unroll
    for (int k = 0; k < 8; ++k) {
        const int w = wl + 8 * k;
        if (w0 + w < FW) {
            const unsigned p = (unsigned)f2bf(tile[w][2 * cd])
                             | ((unsigned)f2bf(tile[w][2 * cd + 1]) << 16);
            const size_t pix = (size_t)bh * FW + w0 + w;
            dstu[pix * (CH / 2) + (c0 >> 1) + cd] = p;
        }
    }
}

// ---------- Pass 2: ROIAlign on channels-last bf16 featT ----------
__global__ __launch_bounds__(256) void roialign_cl_kernel(
    const unsigned short* __restrict__ featT,
    const float* __restrict__ rois,
    float* __restrict__ out, int N) {
    __shared__ int   s_yl[SY], s_yh[SY];          // offsets in ushort elements
    __shared__ float s_ly[SY], s_hy[SY];
    __shared__ int   s_xl[SX], s_xh[SX];
    __shared__ float s_lx[SX], s_hx[SX];
    __shared__ unsigned short s_out16[CH * BINS]; // 25 KB bf16 staging

    const int n   = blockIdx.x;
    const int tid = threadIdx.x;
    const float* __restrict__ roi = rois + (size_t)n * 5;

    if (tid < SY + SX) {
        const bool isy = (tid < SY);
        const int  idx = isy ? tid : tid - SY;
        const int  lim = isy ? FH : FW;
        const float start = (isy ? roi[2] : roi[1]) * 0.25f;
        const float end_  = (isy ? roi[4] : roi[3]) * 0.25f;
        const float len   = fmaxf(end_ - start, 1.0f);
        const float binsz = len * (isy ? (1.0f / PH) : (1.0f / PW));
        const float s = start + ((float)idx + 0.5f) * (1.0f / SR) * binsz;
        const float valid = (s > -1.0f && s < (float)lim) ? 1.0f : 0.0f;
        const float cc = fminf(fmaxf(s, 0.0f), (float)(lim - 1));
        const int   lo = (int)floorf(cc);
        const int   hi = min(lo + 1, lim - 1);
        const float l  = (cc - (float)lo) * valid;
        const float hw = (1.0f - (cc - (float)lo)) * valid;
        if (isy) { s_yl[idx] = lo * (FW * CH); s_yh[idx] = hi * (FW * CH);
                   s_ly[idx] = l; s_hy[idx] = hw; }
        else     { s_xl[idx] = lo * CH;        s_xh[idx] = hi * CH;
                   s_lx[idx] = l; s_hx[idx] = hw; }
    }
    __syncthreads();

    const int b    = (int)roi[0];
    const int m    = tid & 127;               // channel-pair index
    const int half = tid >> 7;                // bins [0,25) or [25,49)
    const int c    = m * 2;
    const unsigned short* __restrict__ fbu =
        featT + (size_t)b * (FH * FW * CH) + c;

    const int bstart = half ? 25 : 0;
    const int bend   = half ? 49 : 25;

    #pragma unroll 1
    for (int bin = bstart; bin < bend; ++bin) {
        const int ph = bin / 7;
        const int pw = bin - ph * 7;
        const int sy = ph * SR, sx = pw * SR;
        float a0 = 0.0f, a1 = 0.0f;
        #pragma unroll
        for (int i = 0; i < SR; ++i) {
            const int   yo0 = s_yl[sy + i], yo1 = s_yh[sy + i];
            const float wy1 = s_ly[sy + i], wy0 = s_hy[sy + i];
            #pragma unroll
            for (int j = 0; j < SR; ++j) {
                const int   xo0 = s_xl[sx + j], xo1 = s_xh[sx + j];
                const float wx1 = s_lx[sx + j], wx0 = s_hx[sx + j];
                const unsigned u00 = *(const unsigned*)(fbu + yo0 + xo0);
                const unsigned u01 = *(const unsigned*)(fbu + yo0 + xo1);
                const unsigned u10 = *(const unsigned*)(fbu + yo1 + xo0);
                const unsigned u11 = *(const unsigned*)(fbu + yo1 + xo1);
                const float w00 = wy0 * wx0, w01 = wy0 * wx1;
                const float w10 = wy1 * wx0, w11 = wy1 * wx1;
                a0 += w00 * bflo(u00) + w01 * bflo(u01) + w10 * bflo(u10) + w11 * bflo(u11);
                a1 += w00 * bfhi(u00) + w01 * bfhi(u01) + w10 * bfhi(u10) + w11 * bfhi(u11);
            }
        }
        s_out16[c * BINS + bin]       = f2bf(a0 * 0.25f);
        s_out16[(c + 1) * BINS + bin] = f2bf(a1 * 0.25f);
    }
    __syncthreads();

    // Coalesced fp32 flush of this ROI's [C, 7, 7] tile
    float* __restrict__ outn = out + (size_t)n * (CH * BINS);
    #pragma unroll
    for (int k = 0; k < BINS; ++k) {
        const int e = k * 256 + tid;
        outn[e] = bflo((unsigned)s_out16[e]);
    }
}

// ---------- Fallback (fp32, no workspace) ----------
__global__ __launch_bounds__(256) void roialign_kernel(
    const float* __restrict__ feat,
    const float* __restrict__ rois,
    float* __restrict__ out, int N) {
    __shared__ int   s_yl[SY], s_yh[SY];
    __shared__ float s_ly[SY], s_hy[SY];
    __shared__ int   s_xl[SX], s_xh[SX];
    __shared__ float s_lx[SX], s_hx[SX];
    __shared__ float s_out[CH * BINS];

    const int n   = blockIdx.x;
    const int tid = threadIdx.x;
    const float* __restrict__ roi = rois + (size_t)n * 5;

    if (tid < SY + SX) {
        const bool isy = (tid < SY);
        const int  idx = isy ? tid : tid - SY;
        const int  lim = isy ? FH : FW;
        const float start = (isy ? roi[2] : roi[1]) * 0.25f;
        const float end_  = (isy ? roi[4] : roi[3]) * 0.25f;
        const float len   = fmaxf(end_ - start, 1.0f);
        const float binsz = len * (isy ? (1.0f / PH) : (1.0f / PW));
        const float s = start + ((float)idx + 0.5f) * (1.0f / SR) * binsz;
        const float valid = (s > -1.0f && s < (float)lim) ? 1.0f : 0.0f;
        const float cc = fminf(fmaxf(s, 0.0f), (float)(lim - 1));
        const int   lo = (int)floorf(cc);
        const int   hi = min(lo + 1, lim - 1);
        const float l  = (cc - (float)lo) * valid;
        const float hw = (1.0f - (cc - (float)lo)) * valid;
        if (isy) { s_yl[idx] = lo; s_yh[idx] = hi; s_ly[idx] = l; s_hy[idx] = hw; }
        else     { s_xl[idx] = lo; s_xh[idx] = hi; s_lx[idx] = l; s_hx[idx] = hw; }
    }
    __syncthreads();

    const int b = (int)roi[0];
    const int c = tid;
    const float* __restrict__ fp = feat + ((size_t)b * CH + c) * (size_t)NPIX;

    #pragma unroll 1
    for (int ph = 0; ph < PH; ++ph) {
        const int sy0 = ph * SR;
        const float* r00 = fp + s_yl[sy0] * FW;
        const float* r01 = fp + s_yh[sy0] * FW;
        const float* r10 = fp + s_yl[sy0 + 1] * FW;
        const float* r11 = fp + s_yh[sy0 + 1] * FW;
        const float ly0 = s_ly[sy0],     hy0 = s_hy[sy0];
        const float ly1 = s_ly[sy0 + 1], hy1 = s_hy[sy0 + 1];
        for (int pw = 0; pw < PW; ++pw) {
            const int sx0 = pw * SR;
            float acc = 0.0f;
            #pragma unroll
            for (int j = 0; j < SR; ++j) {
                const int   xl = s_xl[sx0 + j], xh = s_xh[sx0 + j];
                const float lx = s_lx[sx0 + j], hx = s_hx[sx0 + j];
                acc += hy0 * (hx * r00[xl] + lx * r00[xh])
                     + ly0 * (hx * r01[xl] + lx * r01[xh]);
                acc += hy1 * (hx * r10[xl] + lx * r10[xh])
                     + ly1 * (hx * r11[xl] + lx * r11[xh]);
            }
            s_out[c * BINS + ph * PW + pw] = acc * 0.25f;
        }
    }
    __syncthreads();

    float* __restrict__ outn = out + (size_t)n * (CH * BINS);
    #pragma unroll
    for (int k = 0; k < BINS; ++k) {
        const int idx = k * 256 + tid;
        outn[idx] = s_out[idx];
    }
}

extern "C" void kernel_launch(void* const* d_in, const int* in_sizes, int n_in,
                              void* d_out, int out_size, void* d_ws, size_t ws_size,
                              hipStream_t stream) {
    const float* feat = (const float*)d_in[0];
    const float* rois = (const float*)d_in[1];
    float* out = (float*)d_out;
    const int N = in_sizes[1] / 5;
    const int B = in_sizes[0] / (CH * NPIX);
    const size_t need = (size_t)B * CH * NPIX * sizeof(unsigned short);

    if (ws_size >= need) {
        unsigned short* featT = (unsigned short*)d_ws;
        dim3 tgrid((FW + 63) / 64, CH / 64, B * FH);
        transpose_kernel<<<tgrid, 256, 0, stream>>>(feat, featT);
        roialign_cl_kernel<<<N, 256, 0, stream>>>(featT, rois, out, N);
    } else {
        roialign_kernel<<<N, 256, 0, stream>>>(feat, rois, out, N);
    }
}

// Round 4
// 223.861 us; speedup vs baseline: 5.1007x; 1.0247x over previous
//
#include <hip/hip_runtime.h>

#define PH 7
#define PW 7
#define SR 2
#define SY (PH * SR)   // 14
#define SX (PW * SR)   // 14
#define CH 256
#define FH 200
#define FW 272
#define BINS (PH * PW) // 49
#define NPIX (FH * FW) // 54400

__device__ __forceinline__ unsigned short f2bf(float f) {
    unsigned x = __float_as_uint(f);
    return (unsigned short)((x + 0x7fffu + ((x >> 16) & 1u)) >> 16);
}
__device__ __forceinline__ float bflo(unsigned u) { return __uint_as_float(u << 16); }
__device__ __forceinline__ float bfhi(unsigned u) { return __uint_as_float(u & 0xffff0000u); }

// ---------- Pass 1: feat [B,C,H,W] fp32 -> featT [B,H,W,C] bf16 ----------
// One block per (b*FH+h, c-group-of-64): reads 64 full rows of 1088 B
// (sequential DRAM streams), stages bf16 in LDS, writes 128 B-aligned chunks.
__global__ __launch_bounds__(256) void transpose_kernel(
    const float* __restrict__ feat, unsigned short* __restrict__ featT) {
    __shared__ unsigned short tile[FW][64];   // 34816 B, [w][c_local]
    const int t  = threadIdx.x;
    const int bh = blockIdx.x;                // b*FH + h
    const int c0 = blockIdx.y * 64;
    const int b  = bh / FH;
    const int h  = bh % FH;

    // Load: 4 lanes per channel row, 17 float4 each (68 float4 = 272 w)
    const int cl  = t >> 2;                   // 0..63
    const int wq0 = t & 3;
    const float* __restrict__ src =
        feat + (size_t)b * CH * NPIX + (size_t)(c0 + cl) * NPIX + (size_t)h * FW;
    #pragma unroll
    for (int k = 0; k < 17; ++k) {
        const int fidx = wq0 + 4 * k;         // 0..67
        const float4 v = *(const float4*)(src + fidx * 4);
        const int w = fidx * 4;
        tile[w + 0][cl] = f2bf(v.x);
        tile[w + 1][cl] = f2bf(v.y);
        tile[w + 2][cl] = f2bf(v.z);
        tile[w + 3][cl] = f2bf(v.w);
    }
    __syncthreads();

    // Store: per w, 64 bf16 = 32 dwords = 128 B aligned chunk (no RMW)
    const int cd = t & 31;                    // c-pair
    const int wl = t >> 5;                    // 0..7
    unsigned* __restrict__ dstu = (unsigned*)featT;
    const size_t pixbase = (size_t)bh * FW;
    #pragma unroll
    for (int k = 0; k < 34; ++k) {
        const int w = wl + 8 * k;             // 272 = 8*34
        const unsigned p = *(const unsigned*)&tile[w][2 * cd];
        dstu[(pixbase + w) * (CH / 2) + (c0 >> 1) + cd] = p;
    }
}

// ---------- Pass 2: ROIAlign on channels-last bf16 featT ----------
__global__ __launch_bounds__(256) void roialign_cl_kernel(
    const unsigned short* __restrict__ featT,
    const float* __restrict__ rois,
    float* __restrict__ out, int N) {
    __shared__ int   s_yl[SY], s_yh[SY];          // offsets in DWORDS
    __shared__ float s_ly[SY], s_hy[SY];          // 0.5*weight, validity folded
    __shared__ int   s_xl[SX], s_xh[SX];
    __shared__ float s_lx[SX], s_hx[SX];
    __shared__ unsigned short s_out16[CH * BINS]; // 25 KB bf16 staging

    const int n   = blockIdx.x;
    const int tid = threadIdx.x;
    const float* __restrict__ roi = rois + (size_t)n * 5;

    if (tid < SY + SX) {
        const bool isy = (tid < SY);
        const int  idx = isy ? tid : tid - SY;
        const int  lim = isy ? FH : FW;
        const float start = (isy ? roi[2] : roi[1]) * 0.25f;
        const float end_  = (isy ? roi[4] : roi[3]) * 0.25f;
        const float len   = fmaxf(end_ - start, 1.0f);
        const float binsz = len * (isy ? (1.0f / PH) : (1.0f / PW));
        const float s = start + ((float)idx + 0.5f) * (1.0f / SR) * binsz;
        const float valid = (s > -1.0f && s < (float)lim) ? 0.5f : 0.0f; // fold 1/SR avg
        const float cc = fminf(fmaxf(s, 0.0f), (float)(lim - 1));
        const int   lo = (int)floorf(cc);
        const int   hi = min(lo + 1, lim - 1);
        const float l  = (cc - (float)lo) * valid;
        const float hw = (1.0f - (cc - (float)lo)) * valid;
        const int   rowstride = FW * (CH / 2);     // dwords per y
        if (isy) { s_yl[idx] = lo * rowstride; s_yh[idx] = hi * rowstride;
                   s_ly[idx] = l; s_hy[idx] = hw; }
        else     { s_xl[idx] = lo * (CH / 2);  s_xh[idx] = hi * (CH / 2);
                   s_lx[idx] = l; s_hx[idx] = hw; }
    }
    __syncthreads();

    const int b = (int)roi[0];
    const int q = tid & 63;               // channel-quad: channels 4q..4q+3
    const int g = tid >> 6;               // wave -> bin group
    const unsigned* __restrict__ fbu =
        (const unsigned*)featT + (size_t)b * (FH * FW * (CH / 2)) + q * 2;

    const int bstart = g * 12;
    const int bend   = (g == 3) ? 49 : (g + 1) * 12;

    #pragma unroll 1
    for (int bin = bstart; bin < bend; ++bin) {
        const int ph = bin / 7;
        const int pw = bin - ph * 7;
        const int sy = ph * SR, sx = pw * SR;
        float a0 = 0.f, a1 = 0.f, a2 = 0.f, a3 = 0.f;
        #pragma unroll
        for (int i = 0; i < SR; ++i) {
            const int   yo0 = s_yl[sy + i], yo1 = s_yh[sy + i];
            const float wy1 = s_ly[sy + i], wy0 = s_hy[sy + i];
            #pragma unroll
            for (int j = 0; j < SR; ++j) {
                const int   xo0 = s_xl[sx + j], xo1 = s_xh[sx + j];
                const float wx1 = s_lx[sx + j], wx0 = s_hx[sx + j];
                const uint2 u00 = *(const uint2*)(fbu + yo0 + xo0);
                const uint2 u01 = *(const uint2*)(fbu + yo0 + xo1);
                const uint2 u10 = *(const uint2*)(fbu + yo1 + xo0);
                const uint2 u11 = *(const uint2*)(fbu + yo1 + xo1);
                const float w00 = wy0 * wx0, w01 = wy0 * wx1;
                const float w10 = wy1 * wx0, w11 = wy1 * wx1;
                a0 += w00 * bflo(u00.x) + w01 * bflo(u01.x) + w10 * bflo(u10.x) + w11 * bflo(u11.x);
                a1 += w00 * bfhi(u00.x) + w01 * bfhi(u01.x) + w10 * bfhi(u10.x) + w11 * bfhi(u11.x);
                a2 += w00 * bflo(u00.y) + w01 * bflo(u01.y) + w10 * bflo(u10.y) + w11 * bflo(u11.y);
                a3 += w00 * bfhi(u00.y) + w01 * bfhi(u01.y) + w10 * bfhi(u10.y) + w11 * bfhi(u11.y);
            }
        }
        const int c4 = q * 4;
        s_out16[(c4 + 0) * BINS + bin] = f2bf(a0);
        s_out16[(c4 + 1) * BINS + bin] = f2bf(a1);
        s_out16[(c4 + 2) * BINS + bin] = f2bf(a2);
        s_out16[(c4 + 3) * BINS + bin] = f2bf(a3);
    }
    __syncthreads();

    // Coalesced fp32 flush of this ROI's [C, 7, 7] tile
    float* __restrict__ outn = out + (size_t)n * (CH * BINS);
    #pragma unroll
    for (int k = 0; k < BINS; ++k) {
        const int e = k * 256 + tid;
        outn[e] = bflo((unsigned)s_out16[e]);
    }
}

// ---------- Fallback (fp32, no workspace) ----------
__global__ __launch_bounds__(256) void roialign_kernel(
    const float* __restrict__ feat,
    const float* __restrict__ rois,
    float* __restrict__ out, int N) {
    __shared__ int   s_yl[SY], s_yh[SY];
    __shared__ float s_ly[SY], s_hy[SY];
    __shared__ int   s_xl[SX], s_xh[SX];
    __shared__ float s_lx[SX], s_hx[SX];
    __shared__ float s_out[CH * BINS];

    const int n   = blockIdx.x;
    const int tid = threadIdx.x;
    const float* __restrict__ roi = rois + (size_t)n * 5;

    if (tid < SY + SX) {
        const bool isy = (tid < SY);
        const int  idx = isy ? tid : tid - SY;
        const int  lim = isy ? FH : FW;
        const float start = (isy ? roi[2] : roi[1]) * 0.25f;
        const float end_  = (isy ? roi[4] : roi[3]) * 0.25f;
        const float len   = fmaxf(end_ - start, 1.0f);
        const float binsz = len * (isy ? (1.0f / PH) : (1.0f / PW));
        const float s = start + ((float)idx + 0.5f) * (1.0f / SR) * binsz;
        const float valid = (s > -1.0f && s < (float)lim) ? 1.0f : 0.0f;
        const float cc = fminf(fmaxf(s, 0.0f), (float)(lim - 1));
        const int   lo = (int)floorf(cc);
        const int   hi = min(lo + 1, lim - 1);
        const float l  = (cc - (float)lo) * valid;
        const float hw = (1.0f - (cc - (float)lo)) * valid;
        if (isy) { s_yl[idx] = lo; s_yh[idx] = hi; s_ly[idx] = l; s_hy[idx] = hw; }
        else     { s_xl[idx] = lo; s_xh[idx] = hi; s_lx[idx] = l; s_hx[idx] = hw; }
    }
    __syncthreads();

    const int b = (int)roi[0];
    const int c = tid;
    const float* __restrict__ fp = feat + ((size_t)b * CH + c) * (size_t)NPIX;

    #pragma unroll 1
    for (int ph = 0; ph < PH; ++ph) {
        const int sy0 = ph * SR;
        const float* r00 = fp + s_yl[sy0] * FW;
        const float* r01 = fp + s_yh[sy0] * FW;
        const float* r10 = fp + s_yl[sy0 + 1] * FW;
        const float* r11 = fp + s_yh[sy0 + 1] * FW;
        const float ly0 = s_ly[sy0],     hy0 = s_hy[sy0];
        const float ly1 = s_ly[sy0 + 1], hy1 = s_hy[sy0 + 1];
        for (int pw = 0; pw < PW; ++pw) {
            const int sx0 = pw * SR;
            float acc = 0.0f;
            #pragma unroll
            for (int j = 0; j < SR; ++j) {
                const int   xl = s_xl[sx0 + j], xh = s_xh[sx0 + j];
                const float lx = s_lx[sx0 + j], hx = s_hx[sx0 + j];
                acc += hy0 * (hx * r00[xl] + lx * r00[xh])
                     + ly0 * (hx * r01[xl] + lx * r01[xh]);
                acc += hy1 * (hx * r10[xl] + lx * r10[xh])
                     + ly1 * (hx * r11[xl] + lx * r11[xh]);
            }
            s_out[c * BINS + ph * PW + pw] = acc * 0.25f;
        }
    }
    __syncthreads();

    float* __restrict__ outn = out + (size_t)n * (CH * BINS);
    #pragma unroll
    for (int k = 0; k < BINS; ++k) {
        const int idx = k * 256 + tid;
        outn[idx] = s_out[idx];
    }
}

extern "C" void kernel_launch(void* const* d_in, const int* in_sizes, int n_in,
                              void* d_out, int out_size, void* d_ws, size_t ws_size,
                              hipStream_t stream) {
    const float* feat = (const float*)d_in[0];
    const float* rois = (const float*)d_in[1];
    float* out = (float*)d_out;
    const int N = in_sizes[1] / 5;
    const int B = in_sizes[0] / (CH * NPIX);
    const size_t need = (size_t)B * CH * NPIX * sizeof(unsigned short);

    if (ws_size >= need) {
        unsigned short* featT = (unsigned short*)d_ws;
        dim3 tgrid(B * FH, CH / 64);
        transpose_kernel<<<tgrid, 256, 0, stream>>>(feat, featT);
        roialign_cl_kernel<<<N, 256, 0, stream>>>(featT, rois, out, N);
    } else {
        roialign_kernel<<<N, 256, 0, stream>>>(feat, rois, out, N);
    }
}